// Round 7
// baseline (45186.618 us; speedup 1.0000x reference)
//
#include <hip/hip_runtime.h>
#include <hip/hip_bf16.h>

typedef unsigned short u16;
typedef unsigned int u32;
typedef unsigned long long u64;
typedef __fp16 f16x2 __attribute__((ext_vector_type(2)));

// ---------- sizes ----------
#define T_  8192
#define F_  1024
#define H_  2048
#define G_  8192   // 4*H

#define NB    128   // recurrence blocks
#define UPB   16    // hidden units per block
#define NREG  16    // replicated exchange regions
#define DSLOT 4     // ring depth (skew bound 2; 4 for margin)

// ws layout (bytes). Total ~172 MB.
#define WS_XG    0                    // bf16 [T][G]          134217728
#define WS_ABF   134217728ull         // bf16 [T][F]           16777216
#define WS_WBF   150994944ull         // bf16 [G][F]           16777216
#define WS_TAG   167772160ull         // u64 [16][4][128]         65536
#define WS_DAT   167837696ull         // u64 [16][4][512]        262144
#define WS_PART  168099840ull         // f32 [T][128]           4194304

static __device__ __forceinline__ float bf2f(u16 u) {
    union { u32 i; float f; } x; x.i = ((u32)u) << 16; return x.f;
}
static __device__ __forceinline__ u16 f2bf(float f) {
    union { float f; u32 u; } x; x.f = f;
    u32 r = (x.u + 0x7fffu + ((x.u >> 16) & 1u)) >> 16;
    return (u16)r;
}

// ---------- fp32 -> bf16 convert (4 elems/thread) ----------
__global__ void cvt4_kernel(const float* __restrict__ s, u16* __restrict__ d, int n4) {
    int i = blockIdx.x * 256 + threadIdx.x;
    if (i < n4) {
        float4 v = ((const float4*)s)[i];
        union { u16 h[4]; uint2 v2; } o;
        o.h[0] = f2bf(v.x); o.h[1] = f2bf(v.y); o.h[2] = f2bf(v.z); o.h[3] = f2bf(v.w);
        ((uint2*)d)[i] = o.v2;
    }
}

// ---------- x_gates GEMM: xg[t][g] = sum_f A[t][f]*W[g][f] + b_ih[g]+b_hh[g] ----------
__global__ __launch_bounds__(256) void gemm_xg_kernel(
    const u16* __restrict__ A, const u16* __restrict__ W,
    const float* __restrict__ b_ih, const float* __restrict__ b_hh,
    u16* __restrict__ xg)
{
    __shared__ u16 As[64][40];
    __shared__ u16 Ws[64][40];

    const int tb = blockIdx.y * 64;
    const int gb = blockIdx.x * 64;
    const int tid  = threadIdx.x;
    const int wave = tid >> 6;
    const int lane = tid & 63;
    const int m    = lane & 15;
    const int quad = lane >> 4;

    const int lrow = tid >> 2;
    const int lcol = (tid & 3) * 8;

    using frag  = __attribute__((ext_vector_type(8))) short;
    using f32x4 = __attribute__((ext_vector_type(4))) float;
    f32x4 acc[4] = {};

    for (int k0 = 0; k0 < F_; k0 += 32) {
        __syncthreads();
        *(uint4*)&As[lrow][lcol] = *(const uint4*)&A[(size_t)(tb + lrow) * F_ + k0 + lcol];
        *(uint4*)&Ws[lrow][lcol] = *(const uint4*)&W[(size_t)(gb + lrow) * F_ + k0 + lcol];
        __syncthreads();
        frag bfr = *(const frag*)&Ws[wave * 16 + m][quad * 8];
#pragma unroll
        for (int i = 0; i < 4; ++i) {
            frag afr = *(const frag*)&As[i * 16 + m][quad * 8];
            acc[i] = __builtin_amdgcn_mfma_f32_16x16x32_bf16(afr, bfr, acc[i], 0, 0, 0);
        }
    }
    const int g = gb + wave * 16 + m;
    const float bias = b_ih[g] + b_hh[g];
#pragma unroll
    for (int i = 0; i < 4; ++i)
#pragma unroll
        for (int r = 0; r < 4; ++r) {
            int t = tb + i * 16 + quad * 4 + r;
            xg[(size_t)t * G_ + g] = f2bf(acc[i][r] + bias);
        }
}

// ---------- persistent LSTM recurrence: tag/bulk split exchange ----------
// 128 blocks x 512 threads; block owns units [b*16, b*16+16).
// Wave w computes units 2w, 2w+1 (8 gate rows); lane owns 32 cols as 16 f16x2.
// Exchange per step: producer stores 4 data u64 (16 bf16 h) to each of 16
// regions, s_waitcnt vmcnt(0), then tag[region][slot][b] = t. Consumers spin
// on tags only (threads 0..127, 1 KB footprint), barrier, bulk-read 4 KB once.
__global__ __launch_bounds__(512, 2) void lstm_rec_kernel(
    const float* __restrict__ Whh,   // [G][H] f32
    const u16*  __restrict__ xg,     // [T][G] bf16
    const float* __restrict__ Wout,  // [H]
    u64*  __restrict__ tag,          // [16][4][128], pre-filled 0xFF
    u64*  __restrict__ dat,          // [16][4][512]
    float* __restrict__ part)        // [T][128]
{
    __shared__ u32 hs2[H_ / 2];      // h as packed f16x2
    __shared__ float hv[UPB];
    __shared__ float pl[UPB];

    const int b   = blockIdx.x;
    const int tid = threadIdx.x;
    const int w   = tid >> 6;
    const int l   = tid & 63;

    // weights: acc j = u*4+r -> gate row r of unit b*16+2w+u, cols 2l+128kc(+1)
    f16x2 wreg[8][16];
#pragma unroll
    for (int u = 0; u < 2; ++u)
#pragma unroll
        for (int r = 0; r < 4; ++r) {
            const float* wrow = Whh + (size_t)(r * H_ + b * UPB + 2 * w + u) * H_;
#pragma unroll
            for (int kc = 0; kc < 16; ++kc) {
                float2 v = *(const float2*)&wrow[2 * l + 128 * kc];
                wreg[u * 4 + r][kc] = __builtin_amdgcn_cvt_pkrtz(v.x, v.y);
            }
        }
    const int myunit = b * UPB + 2 * w + l;   // meaningful for l<2
    float wout = 0.f, c = 0.f;
    if (l < 2) wout = Wout[myunit];

    // h_{-1} = 0
    hs2[tid] = 0; hs2[tid + 512] = 0;
    __syncthreads();

    // xg pipeline regs (lanes 0,1 of each wave)
    float xgi = 0.f, xgf = 0.f, xgg = 0.f, xgo = 0.f;
    if (l < 2) {
        const u16* xr = &xg[myunit];
        xgi = bf2f(xr[0]); xgf = bf2f(xr[2048]);
        xgg = bf2f(xr[4096]); xgo = bf2f(xr[6144]);
    }

    const int rg = b & (NREG - 1);
    const u64* mytag = tag + (size_t)rg * DSLOT * 128;
    const u64* mydat = dat + (size_t)rg * DSLOT * 512;

    for (int t = 0; t < T_; ++t) {
        // prefetch next step's xg (a full step of slack)
        float nxi = 0.f, nxf = 0.f, nxg = 0.f, nxo = 0.f;
        if (l < 2 && t + 1 < T_) {
            const u16* xr = &xg[(size_t)(t + 1) * G_ + myunit];
            nxi = bf2f(xr[0]); nxf = bf2f(xr[2048]);
            nxg = bf2f(xr[4096]); nxo = bf2f(xr[6144]);
        }

        float a[8] = {};
#pragma unroll
        for (int kc = 0; kc < 16; ++kc) {
            union { u32 u; f16x2 h; } hw;
            hw.u = hs2[l + 64 * kc];
#pragma unroll
            for (int j = 0; j < 8; ++j)
                a[j] = __builtin_amdgcn_fdot2(wreg[j][kc], hw.h, a[j], false);
        }
#pragma unroll
        for (int off = 32; off >= 1; off >>= 1)
#pragma unroll
            for (int j = 0; j < 8; ++j)
                a[j] += __shfl_xor(a[j], off);

        if (l < 2) {
            float gi = a[l * 4 + 0] + xgi, gf = a[l * 4 + 1] + xgf;
            float gg = a[l * 4 + 2] + xgg, go = a[l * 4 + 3] + xgo;
            float i_ = 1.f / (1.f + __expf(-gi));
            float f_ = 1.f / (1.f + __expf(-gf));
            float g_ = 1.f - 2.f / (__expf(2.f * gg) + 1.f);   // tanh
            float o_ = 1.f / (1.f + __expf(-go));
            c = fmaf(f_, c, i_ * g_);
            float th = 1.f - 2.f / (__expf(2.f * c) + 1.f);    // tanh
            float hval = o_ * th;
            hv[2 * w + l] = hval;
            pl[2 * w + l] = hval * wout;
        }
        xgi = nxi; xgf = nxf; xgg = nxg; xgo = nxo;
        __syncthreads();   // B1: hv/pl complete

        const int slot = t & (DSLOT - 1);

        // publish: thread j < 16 handles region j: 4 data u64, waitcnt, 1 tag
        if (tid < NREG) {
            u64* dd = dat + ((size_t)tid * DSLOT + slot) * 512 + 4 * b;
#pragma unroll
            for (int q = 0; q < 4; ++q) {
                u64 v = (u64)f2bf(hv[4 * q + 0])
                      | ((u64)f2bf(hv[4 * q + 1]) << 16)
                      | ((u64)f2bf(hv[4 * q + 2]) << 32)
                      | ((u64)f2bf(hv[4 * q + 3]) << 48);
                __hip_atomic_store(&dd[q], v, __ATOMIC_RELAXED, __HIP_MEMORY_SCOPE_AGENT);
            }
            __asm__ volatile("s_waitcnt vmcnt(0)" ::: "memory");
            __hip_atomic_store(&tag[((size_t)tid * DSLOT + slot) * 128 + b], (u64)t,
                               __ATOMIC_RELAXED, __HIP_MEMORY_SCOPE_AGENT);
        }
        if (tid == 511) {
            float s = 0.f;
#pragma unroll
            for (int j = 0; j < UPB; ++j) s += pl[j];
            part[(size_t)t * NB + b] = s;
        }

        // poll tags only (threads 0..127, one producer each)
        if (tid < NB) {
            const u64* tp = mytag + (size_t)slot * 128 + tid;
            while (__hip_atomic_load(tp, __ATOMIC_RELAXED, __HIP_MEMORY_SCOPE_AGENT)
                   != (u64)t) { }
        }
        __syncthreads();   // B2: all 128 tags == t -> all data visible at LLC

        // bulk read: thread tid reads u64 tid -> h units 4*tid..4*tid+3
        {
            u64 v = __hip_atomic_load(mydat + (size_t)slot * 512 + tid,
                                      __ATOMIC_RELAXED, __HIP_MEMORY_SCOPE_AGENT);
            float f0 = bf2f((u16)v),         f1 = bf2f((u16)(v >> 16));
            float f2v = bf2f((u16)(v >> 32)), f3 = bf2f((u16)(v >> 48));
            union { f16x2 h; u32 u; } p0, p1;
            p0.h = __builtin_amdgcn_cvt_pkrtz(f0, f1);
            p1.h = __builtin_amdgcn_cvt_pkrtz(f2v, f3);
            hs2[2 * tid]     = p0.u;
            hs2[2 * tid + 1] = p1.u;
        }
        __syncthreads();   // B3: hs2 ready for next step
    }
}

// ---------- final: out[t] = b_out + sum_b part[t][b] ----------
__global__ __launch_bounds__(256) void out_reduce_kernel(
    const float* __restrict__ part, const float* __restrict__ b_out,
    float* __restrict__ out)
{
    int t = blockIdx.x * 4 + (threadIdx.x >> 6);
    int l = threadIdx.x & 63;
    const float* p = &part[(size_t)t * NB];
    float s = p[l] + p[l + 64];
#pragma unroll
    for (int off = 32; off >= 1; off >>= 1) s += __shfl_down(s, off);
    if (l == 0) out[t] = s + b_out[0];
}

extern "C" void kernel_launch(void* const* d_in, const int* in_sizes, int n_in,
                              void* d_out, int out_size, void* d_ws, size_t ws_size,
                              hipStream_t stream) {
    const float* input = (const float*)d_in[0];
    const float* W_ih  = (const float*)d_in[1];
    const float* W_hh  = (const float*)d_in[2];
    const float* b_ih  = (const float*)d_in[3];
    const float* b_hh  = (const float*)d_in[4];
    const float* W_out = (const float*)d_in[5];
    const float* b_out = (const float*)d_in[6];
    float* out = (float*)d_out;

    char* ws = (char*)d_ws;
    u16*   xg   = (u16*)(ws + WS_XG);
    u16*   Abf  = (u16*)(ws + WS_ABF);
    u16*   Wbf  = (u16*)(ws + WS_WBF);
    u64*   tagp = (u64*)(ws + WS_TAG);
    u64*   datp = (u64*)(ws + WS_DAT);
    float* part = (float*)(ws + WS_PART);

    // tags init to 0xFF.. (never equals any t); data needs no init (tag-gated)
    (void)hipMemsetAsync(tagp, 0xFF, (size_t)NREG * DSLOT * 128 * sizeof(u64), stream);

    const int n4 = (T_ * F_) / 4;
    cvt4_kernel<<<(n4 + 255) / 256, 256, 0, stream>>>(input, Abf, n4);
    cvt4_kernel<<<(G_ * F_ / 4 + 255) / 256, 256, 0, stream>>>(W_ih, Wbf, G_ * F_ / 4);

    gemm_xg_kernel<<<dim3(G_ / 64, T_ / 64), 256, 0, stream>>>(Abf, Wbf, b_ih, b_hh, xg);

    lstm_rec_kernel<<<NB, 512, 0, stream>>>(W_hh, xg, W_out, tagp, datp, part);

    out_reduce_kernel<<<T_ / 4, 256, 0, stream>>>(part, b_out, out);
}

// Round 8
// 28084.171 us; speedup vs baseline: 1.6090x; 1.6090x over previous
//
#include <hip/hip_runtime.h>
#include <hip/hip_bf16.h>

typedef unsigned short u16;
typedef unsigned int u32;
typedef unsigned long long u64;
typedef __fp16 f16x2 __attribute__((ext_vector_type(2)));

// ---------- sizes ----------
#define T_  8192
#define F_  1024
#define H_  2048
#define G_  8192   // 4*H

#define NREG  16    // replicated exchange regions
#define DSLOT 4     // ring depth (dataflow skew bound 2; 4 for margin)

// ws layout (bytes). Total ~173 MB.
#define WS_XG    0                    // bf16 [T][G]          134217728
#define WS_ABF   134217728ull         // bf16 [T][F]           16777216
#define WS_WBF   150994944ull         // bf16 [G][F]           16777216
#define WS_HX    167772160ull         // u64 [16][4][1024]       524288
#define WS_PART  168296448ull         // f32 [T][256]           8388608

static __device__ __forceinline__ float bf2f(u16 u) {
    union { u32 i; float f; } x; x.i = ((u32)u) << 16; return x.f;
}
static __device__ __forceinline__ u16 f2bf(float f) {
    union { float f; u32 u; } x; x.f = f;
    u32 r = (x.u + 0x7fffu + ((x.u >> 16) & 1u)) >> 16;
    return (u16)r;
}

// ---------- fp32 -> bf16 convert (4 elems/thread) ----------
__global__ void cvt4_kernel(const float* __restrict__ s, u16* __restrict__ d, int n4) {
    int i = blockIdx.x * 256 + threadIdx.x;
    if (i < n4) {
        float4 v = ((const float4*)s)[i];
        union { u16 h[4]; uint2 v2; } o;
        o.h[0] = f2bf(v.x); o.h[1] = f2bf(v.y); o.h[2] = f2bf(v.z); o.h[3] = f2bf(v.w);
        ((uint2*)d)[i] = o.v2;
    }
}

// ---------- x_gates GEMM: xg[t][g] = sum_f A[t][f]*W[g][f] + b_ih[g]+b_hh[g] ----------
__global__ __launch_bounds__(256) void gemm_xg_kernel(
    const u16* __restrict__ A, const u16* __restrict__ W,
    const float* __restrict__ b_ih, const float* __restrict__ b_hh,
    u16* __restrict__ xg)
{
    __shared__ u16 As[64][40];
    __shared__ u16 Ws[64][40];

    const int tb = blockIdx.y * 64;
    const int gb = blockIdx.x * 64;
    const int tid  = threadIdx.x;
    const int wave = tid >> 6;
    const int lane = tid & 63;
    const int m    = lane & 15;
    const int quad = lane >> 4;

    const int lrow = tid >> 2;
    const int lcol = (tid & 3) * 8;

    using frag  = __attribute__((ext_vector_type(8))) short;
    using f32x4 = __attribute__((ext_vector_type(4))) float;
    f32x4 acc[4] = {};

    for (int k0 = 0; k0 < F_; k0 += 32) {
        __syncthreads();
        *(uint4*)&As[lrow][lcol] = *(const uint4*)&A[(size_t)(tb + lrow) * F_ + k0 + lcol];
        *(uint4*)&Ws[lrow][lcol] = *(const uint4*)&W[(size_t)(gb + lrow) * F_ + k0 + lcol];
        __syncthreads();
        frag bfr = *(const frag*)&Ws[wave * 16 + m][quad * 8];
#pragma unroll
        for (int i = 0; i < 4; ++i) {
            frag afr = *(const frag*)&As[i * 16 + m][quad * 8];
            acc[i] = __builtin_amdgcn_mfma_f32_16x16x32_bf16(afr, bfr, acc[i], 0, 0, 0);
        }
    }
    const int g = gb + wave * 16 + m;
    const float bias = b_ih[g] + b_hh[g];
#pragma unroll
    for (int i = 0; i < 4; ++i)
#pragma unroll
        for (int r = 0; r < 4; ++r) {
            int t = tb + i * 16 + quad * 4 + r;
            xg[(size_t)t * G_ + g] = f2bf(acc[i][r] + bias);
        }
}

// ---------- persistent LSTM recurrence: single-phase tagged exchange, f16 dot2 ----------
// 256 blocks x 512 threads. Wave w owns hidden unit uu = b*8+w (4 gate rows as
// f16x2: 64 VGPRs). Exchange word = [f16x2 h-pair | tag32]; 16 regions x 4 slots
// x 1024 words. Consumers poll their 2 words (data IS the tag) and drop the
// payload straight into LDS as packed f16x2 — no conversion on the poll path.
__global__ __launch_bounds__(512, 2) void lstm_rec_kernel(
    const float* __restrict__ Whh,   // [G][H] f32
    const u16*  __restrict__ xg,     // [T][G] bf16
    const float* __restrict__ Wout,  // [H]
    u64*  __restrict__ hx,           // [16][4][1024] u64, pre-filled 0xFF
    float* __restrict__ part)        // [T][256]
{
    __shared__ u32 hs2[H_ / 2];      // h as packed f16x2 (pair p = units 2p,2p+1)
    __shared__ float hv[8];
    __shared__ float pl[8];

    const int b   = blockIdx.x;
    const int tid = threadIdx.x;
    const int w   = tid >> 6;
    const int l   = tid & 63;
    const int uu  = b * 8 + w;          // hidden unit (wave-uniform)

    // weights (f16): wreg[r][kc] covers h-pair p = l + 64*kc of gate row r
    f16x2 wreg[4][16];
#pragma unroll
    for (int r = 0; r < 4; ++r) {
        const float* wrow = Whh + (size_t)(r * H_ + uu) * H_;
#pragma unroll
        for (int kc = 0; kc < 16; ++kc) {
            float2 v = *(const float2*)&wrow[2 * (l + 64 * kc)];
            wreg[r][kc] = __builtin_amdgcn_cvt_pkrtz(v.x, v.y);
        }
    }
    const float wout = Wout[uu];
    float c = 0.f;

    // h_{-1} = 0
    hs2[tid] = 0; hs2[tid + 512] = 0;
    __syncthreads();

    // xg pipeline regs (lane 0 of each wave)
    float xgi = 0.f, xgf = 0.f, xgg = 0.f, xgo = 0.f;
    if (l == 0) {
        const u16* xr = &xg[uu];
        xgi = bf2f(xr[0]); xgf = bf2f(xr[2048]);
        xgg = bf2f(xr[4096]); xgo = bf2f(xr[6144]);
    }

    const u64* mypoll = hx + (size_t)(b & (NREG - 1)) * DSLOT * 1024;

    for (int t = 0; t < T_; ++t) {
        // prefetch next step's xg (a full step of slack)
        float nxi = 0.f, nxf = 0.f, nxg = 0.f, nxo = 0.f;
        if (l == 0 && t + 1 < T_) {
            const u16* xr = &xg[(size_t)(t + 1) * G_ + uu];
            nxi = bf2f(xr[0]); nxf = bf2f(xr[2048]);
            nxg = bf2f(xr[4096]); nxo = bf2f(xr[6144]);
        }

        float a0 = 0.f, a1 = 0.f, a2 = 0.f, a3 = 0.f;
#pragma unroll
        for (int kc = 0; kc < 16; ++kc) {
            union { u32 u; f16x2 h; } hw;
            hw.u = hs2[l + 64 * kc];
            a0 = __builtin_amdgcn_fdot2(wreg[0][kc], hw.h, a0, false);
            a1 = __builtin_amdgcn_fdot2(wreg[1][kc], hw.h, a1, false);
            a2 = __builtin_amdgcn_fdot2(wreg[2][kc], hw.h, a2, false);
            a3 = __builtin_amdgcn_fdot2(wreg[3][kc], hw.h, a3, false);
        }
#pragma unroll
        for (int off = 32; off >= 1; off >>= 1) {
            a0 += __shfl_xor(a0, off);
            a1 += __shfl_xor(a1, off);
            a2 += __shfl_xor(a2, off);
            a3 += __shfl_xor(a3, off);
        }

        if (l == 0) {
            float gi = a0 + xgi, gf = a1 + xgf, gg = a2 + xgg, go = a3 + xgo;
            float i_ = 1.f / (1.f + __expf(-gi));
            float f_ = 1.f / (1.f + __expf(-gf));
            float g_ = 1.f - 2.f / (__expf(2.f * gg) + 1.f);   // tanh
            float o_ = 1.f / (1.f + __expf(-go));
            c = fmaf(f_, c, i_ * g_);
            float th = 1.f - 2.f / (__expf(2.f * c) + 1.f);    // tanh
            float hval = o_ * th;
            hv[w] = hval;
            pl[w] = hval * wout;
        }
        xgi = nxi; xgf = nxf; xgg = nxg; xgo = nxo;
        __syncthreads();   // B1: hv/pl complete

        const int slot = t & (DSLOT - 1);

        // publish: thread j<64 -> region j>>2, word 4b+(j&3); one store each
        if (tid < 64) {
            const int q = tid & 3, rgn = tid >> 2;
            union { f16x2 h; u32 u; } pk;
            pk.h = __builtin_amdgcn_cvt_pkrtz(hv[2 * q], hv[2 * q + 1]);
            u64 v = ((u64)pk.u << 32) | (u32)t;
            __hip_atomic_store(&hx[((size_t)rgn * DSLOT + slot) * 1024 + 4 * b + q], v,
                               __ATOMIC_RELAXED, __HIP_MEMORY_SCOPE_AGENT);
        }
        if (tid == 511) {
            part[(size_t)t * 256 + b] = pl[0] + pl[1] + pl[2] + pl[3]
                                      + pl[4] + pl[5] + pl[6] + pl[7];
        }

        // poll h_t: thread tid spins on words tid and tid+512 (data IS the tag)
        {
            const u64* pb = mypoll + (size_t)slot * 1024;
            u64 v0 = __hip_atomic_load(pb + tid,       __ATOMIC_RELAXED, __HIP_MEMORY_SCOPE_AGENT);
            u64 v1 = __hip_atomic_load(pb + tid + 512, __ATOMIC_RELAXED, __HIP_MEMORY_SCOPE_AGENT);
            while ((u32)v0 != (u32)t)
                v0 = __hip_atomic_load(pb + tid,       __ATOMIC_RELAXED, __HIP_MEMORY_SCOPE_AGENT);
            while ((u32)v1 != (u32)t)
                v1 = __hip_atomic_load(pb + tid + 512, __ATOMIC_RELAXED, __HIP_MEMORY_SCOPE_AGENT);
            hs2[tid]       = (u32)(v0 >> 32);
            hs2[tid + 512] = (u32)(v1 >> 32);
        }
        __syncthreads();   // B2: hs2 ready for next step
    }
}

// ---------- final: out[t] = b_out + sum_b part[t][b] ----------
__global__ __launch_bounds__(256) void out_reduce_kernel(
    const float* __restrict__ part, const float* __restrict__ b_out,
    float* __restrict__ out)
{
    int t = blockIdx.x * 4 + (threadIdx.x >> 6);
    int l = threadIdx.x & 63;
    const float* p = &part[(size_t)t * 256];
    float s = p[l] + p[l + 64] + p[l + 128] + p[l + 192];
#pragma unroll
    for (int off = 32; off >= 1; off >>= 1) s += __shfl_down(s, off);
    if (l == 0) out[t] = s + b_out[0];
}

extern "C" void kernel_launch(void* const* d_in, const int* in_sizes, int n_in,
                              void* d_out, int out_size, void* d_ws, size_t ws_size,
                              hipStream_t stream) {
    const float* input = (const float*)d_in[0];
    const float* W_ih  = (const float*)d_in[1];
    const float* W_hh  = (const float*)d_in[2];
    const float* b_ih  = (const float*)d_in[3];
    const float* b_hh  = (const float*)d_in[4];
    const float* W_out = (const float*)d_in[5];
    const float* b_out = (const float*)d_in[6];
    float* out = (float*)d_out;

    char* ws = (char*)d_ws;
    u16*   xg   = (u16*)(ws + WS_XG);
    u16*   Abf  = (u16*)(ws + WS_ABF);
    u16*   Wbf  = (u16*)(ws + WS_WBF);
    u64*   hx   = (u64*)(ws + WS_HX);
    float* part = (float*)(ws + WS_PART);

    // tags init to 0xFFFFFFFF (never equals any t in [0,8192))
    (void)hipMemsetAsync(hx, 0xFF, (size_t)NREG * DSLOT * 1024 * sizeof(u64), stream);

    const int n4 = (T_ * F_) / 4;
    cvt4_kernel<<<(n4 + 255) / 256, 256, 0, stream>>>(input, Abf, n4);
    cvt4_kernel<<<(G_ * F_ / 4 + 255) / 256, 256, 0, stream>>>(W_ih, Wbf, G_ * F_ / 4);

    gemm_xg_kernel<<<dim3(G_ / 64, T_ / 64), 256, 0, stream>>>(Abf, Wbf, b_ih, b_hh, xg);

    lstm_rec_kernel<<<256, 512, 0, stream>>>(W_hh, xg, W_out, hx, part);

    out_reduce_kernel<<<T_ / 4, 256, 0, stream>>>(part, b_out, out);
}